// Round 1
// baseline (2333.134 us; speedup 1.0000x reference)
//
#include <hip/hip_runtime.h>
#include <math.h>

// Problem constants
#define B_    2
#define T_    2048
#define DIM_  1024
#define H_    16
#define KV_   4
#define HD_   64
// groups = H_/KV_ = 4

// Workspace layout (in floats)
//   Q    [B][H][T][HD]      4,194,304 f
//   Kt   [B][KV][HD][T]     1,048,576 f   (transposed for LDS d-major staging)
//   V    [B][KV][T][HD]     1,048,576 f
//   attn [B][T][DIM]        4,194,304 f
#define Q_OFF   0u
#define KT_OFF  4194304u
#define V_OFF   (KT_OFF + 1048576u)
#define AT_OFF  (V_OFF + 1048576u)

// ---------------------------------------------------------------------------
// Kernel 1: QKV projection + RoPE epilogue.
// C[4096][1536] = x[4096][1024] @ [Wq | Wk | Wv], 64x64 tiles, BK=16,
// 4x4 per thread. Epilogue routes columns to Q / Kt / V with RoPE on Q,K.
// ---------------------------------------------------------------------------
__global__ __launch_bounds__(256) void qkv_rope_kernel(
    const float* __restrict__ x, const float* __restrict__ sinp,
    const float* __restrict__ cosp,
    const float* __restrict__ Wq, const float* __restrict__ Wk,
    const float* __restrict__ Wv, float* __restrict__ ws)
{
    __shared__ float As[16][68];   // [k][m], pad 68 keeps 16B align + kills conflicts
    __shared__ float Bs[16][68];   // [k][n]

    const int bn = blockIdx.x;     // 0..23  (24 N-tiles of 64)
    const int bm = blockIdx.y;     // 0..63
    const int tid = threadIdx.x;
    const int m0 = bm * 64;

    const float* W; int ldw, c0;
    if (bn < 16)      { W = Wq; ldw = DIM_;     c0 = bn * 64;        }
    else if (bn < 20) { W = Wk; ldw = KV_*HD_;  c0 = bn * 64 - 1024; }
    else              { W = Wv; ldw = KV_*HD_;  c0 = bn * 64 - 1280; }

    const int lrow = tid >> 2;          // 0..63 A-row
    const int lkc  = (tid & 3) * 4;     // k sub-offset
    const int brow = tid >> 4;          // 0..15 B k-row
    const int bcol = (tid & 15) * 4;

    const int tr = (tid >> 4) * 4;      // this thread's 4 rows
    const int tc = (tid & 15) * 4;      // this thread's 4 cols

    float acc[4][4] = {};

    for (int k0 = 0; k0 < DIM_; k0 += 16) {
        float4 av = *(const float4*)&x[(size_t)(m0 + lrow) * DIM_ + k0 + lkc];
        float4 bv = *(const float4*)&W[(size_t)(k0 + brow) * ldw + c0 + bcol];
        __syncthreads();               // previous iteration's reads done
        As[lkc + 0][lrow] = av.x; As[lkc + 1][lrow] = av.y;
        As[lkc + 2][lrow] = av.z; As[lkc + 3][lrow] = av.w;
        *(float4*)&Bs[brow][bcol] = bv;
        __syncthreads();
        #pragma unroll
        for (int kk = 0; kk < 16; ++kk) {
            float4 a = *(const float4*)&As[kk][tr];
            float4 b = *(const float4*)&Bs[kk][tc];
            float af[4] = {a.x, a.y, a.z, a.w};
            float bf[4] = {b.x, b.y, b.z, b.w};
            #pragma unroll
            for (int i = 0; i < 4; ++i)
                #pragma unroll
                for (int j = 0; j < 4; ++j)
                    acc[i][j] += af[i] * bf[j];
        }
    }

    float* Qw  = ws + Q_OFF;
    float* Ktw = ws + KT_OFF;
    float* Vw  = ws + V_OFF;

    #pragma unroll
    for (int i = 0; i < 4; ++i) {
        int m = m0 + tr + i;
        int b = m / T_, t = m % T_;
        if (bn < 20) {
            // RoPE on interleaved pairs (cols tc aligned to 4, head dim 64 -> pairs stay in-thread)
            #pragma unroll
            for (int jp = 0; jp < 2; ++jp) {
                int j   = jp * 2;
                int col = c0 + tc + j;
                int d   = col & 63;
                float ve = acc[i][j], vo = acc[i][j + 1];
                float ce = cosp[t * HD_ + d],     se = sinp[t * HD_ + d];
                float co = cosp[t * HD_ + d + 1], so = sinp[t * HD_ + d + 1];
                float re = ve * ce - vo * se;
                float ro = vo * co + ve * so;
                if (bn < 16) {
                    int h = col >> 6;
                    size_t base = (((size_t)b * H_ + h) * T_ + t) * HD_ + d;
                    Qw[base]     = re;
                    Qw[base + 1] = ro;
                } else {
                    int kv = col >> 6;
                    size_t base = (((size_t)b * KV_ + kv) * HD_ + d) * T_ + t;
                    Ktw[base]      = re;
                    Ktw[base + T_] = ro;   // next d row
                }
            }
        } else {
            int kv = (c0 + tc) >> 6;
            int d  = (c0 + tc) & 63;
            #pragma unroll
            for (int j = 0; j < 4; ++j)
                Vw[(((size_t)b * KV_ + kv) * T_ + t) * HD_ + d + j] = acc[i][j];
        }
    }
}

// ---------------------------------------------------------------------------
// Kernel 2: causal GQA flash attention, f32.
// Block = 256 threads = 4 waves, one (b,h) x 64 q-rows. Wave owns 16 rows.
// Phase 1 lanes-as-keys (K staged d-major), phase 2 lanes-as-dims via LDS P.
// ---------------------------------------------------------------------------
__global__ __launch_bounds__(256) void attn_kernel(
    const float* __restrict__ Qg, const float* __restrict__ Ktg,
    const float* __restrict__ Vg, const float* __restrict__ maskp,
    float* __restrict__ attn_out)
{
    __shared__ float Ql[64][64];   // [row][d]
    __shared__ float Kl[64][64];   // [d][key]   (conflict-free: lanes consecutive keys)
    __shared__ float Vl[64][64];   // [key][d]
    __shared__ float Pl[4][64];    // per-wave P row

    const int tid  = threadIdx.x;
    const int lane = tid & 63;
    const int wid  = tid >> 6;

    const int bi = blockIdx.x;
    const int qt = 31 - (bi & 31);         // descending: long blocks first
    const int bh = bi >> 5;
    const int h  = bh & 15;
    const int b  = bh >> 4;
    const int kvh = h >> 2;                // GQA: h // groups, groups = 4
    const int q0 = qt * 64;

    const float* Qbase = Qg + ((size_t)b * H_ + h) * T_ * HD_;
    const float* Ktb   = Ktg + ((size_t)b * KV_ + kvh) * HD_ * T_;
    const float* Vb    = Vg  + ((size_t)b * KV_ + kvh) * T_ * HD_;

    for (int i = tid; i < 64 * 64; i += 256) {
        int r = i >> 6, d = i & 63;
        Ql[r][d] = Qbase[(size_t)(q0 + r) * HD_ + d];
    }

    float o[16], mreg[16], lreg[16];
    #pragma unroll
    for (int r = 0; r < 16; ++r) { o[r] = 0.f; mreg[r] = -1e30f; lreg[r] = 0.f; }

    for (int kt = 0; kt <= qt; ++kt) {
        const int k0 = kt * 64;
        __syncthreads();
        for (int i = tid; i < 64 * 64; i += 256) {
            int rr = i >> 6, cc = i & 63;
            Kl[rr][cc] = Ktb[(size_t)rr * T_ + k0 + cc];
            Vl[rr][cc] = Vb[(size_t)(k0 + rr) * HD_ + cc];
        }
        __syncthreads();

        const float mval = maskp[b * T_ + k0 + lane];
        const bool diag = (kt == qt);

        #pragma unroll
        for (int r = 0; r < 16; ++r) {
            const int rr = wid * 16 + r;
            const int q  = q0 + rr;
            float s = 0.f;
            #pragma unroll 8
            for (int d = 0; d < 64; ++d)
                s += Ql[rr][d] * Kl[d][lane];
            s *= 0.125f;                           // 1/sqrt(HD)
            if ((diag && (k0 + lane) > q) || mval <= 0.f) s = -1e30f;

            float mx = s;
            #pragma unroll
            for (int off = 32; off >= 1; off >>= 1)
                mx = fmaxf(mx, __shfl_xor(mx, off));
            float mnew = fmaxf(mreg[r], mx);
            float p = __expf(s - mnew);
            float psum = p;
            #pragma unroll
            for (int off = 32; off >= 1; off >>= 1)
                psum += __shfl_xor(psum, off);
            float alpha = __expf(mreg[r] - mnew);
            mreg[r] = mnew;
            lreg[r] = lreg[r] * alpha + psum;

            Pl[wid][lane] = p;
            float accv = o[r] * alpha;
            #pragma unroll 8
            for (int j = 0; j < 64; ++j)
                accv += Pl[wid][j] * Vl[j][lane];
            o[r] = accv;
        }
    }

    #pragma unroll
    for (int r = 0; r < 16; ++r) {
        int q = q0 + wid * 16 + r;
        attn_out[((size_t)b * T_ + q) * DIM_ + h * HD_ + lane] = o[r] / lreg[r];
    }
}

// ---------------------------------------------------------------------------
// Kernel 3: output projection. d_out[4096][1024] = attn[4096][1024] @ Wo
// ---------------------------------------------------------------------------
__global__ __launch_bounds__(256) void outproj_kernel(
    const float* __restrict__ A, const float* __restrict__ Wo,
    float* __restrict__ out)
{
    __shared__ float As[16][68];
    __shared__ float Bs[16][68];

    const int bn = blockIdx.x;     // 0..15
    const int bm = blockIdx.y;     // 0..63
    const int tid = threadIdx.x;
    const int m0 = bm * 64, n0 = bn * 64;

    const int lrow = tid >> 2;
    const int lkc  = (tid & 3) * 4;
    const int brow = tid >> 4;
    const int bcol = (tid & 15) * 4;
    const int tr = (tid >> 4) * 4;
    const int tc = (tid & 15) * 4;

    float acc[4][4] = {};

    for (int k0 = 0; k0 < DIM_; k0 += 16) {
        float4 av = *(const float4*)&A[(size_t)(m0 + lrow) * DIM_ + k0 + lkc];
        float4 bv = *(const float4*)&Wo[(size_t)(k0 + brow) * DIM_ + n0 + bcol];
        __syncthreads();
        As[lkc + 0][lrow] = av.x; As[lkc + 1][lrow] = av.y;
        As[lkc + 2][lrow] = av.z; As[lkc + 3][lrow] = av.w;
        *(float4*)&Bs[brow][bcol] = bv;
        __syncthreads();
        #pragma unroll
        for (int kk = 0; kk < 16; ++kk) {
            float4 a = *(const float4*)&As[kk][tr];
            float4 b = *(const float4*)&Bs[kk][tc];
            float af[4] = {a.x, a.y, a.z, a.w};
            float bf[4] = {b.x, b.y, b.z, b.w};
            #pragma unroll
            for (int i = 0; i < 4; ++i)
                #pragma unroll
                for (int j = 0; j < 4; ++j)
                    acc[i][j] += af[i] * bf[j];
        }
    }

    #pragma unroll
    for (int i = 0; i < 4; ++i) {
        size_t m = m0 + tr + i;
        *(float4*)&out[m * DIM_ + n0 + tc] =
            make_float4(acc[i][0], acc[i][1], acc[i][2], acc[i][3]);
    }
}

// ---------------------------------------------------------------------------
extern "C" void kernel_launch(void* const* d_in, const int* in_sizes, int n_in,
                              void* d_out, int out_size, void* d_ws, size_t ws_size,
                              hipStream_t stream)
{
    const float* x     = (const float*)d_in[0];
    const float* sinp  = (const float*)d_in[1];
    const float* cosp  = (const float*)d_in[2];
    const float* maskp = (const float*)d_in[3];
    const float* Wq    = (const float*)d_in[4];
    const float* Wk    = (const float*)d_in[5];
    const float* Wv    = (const float*)d_in[6];
    const float* Wo    = (const float*)d_in[7];
    float* ws  = (float*)d_ws;
    float* out = (float*)d_out;

    qkv_rope_kernel<<<dim3(24, 64), 256, 0, stream>>>(x, sinp, cosp, Wq, Wk, Wv, ws);
    attn_kernel<<<dim3(B_ * H_ * (T_ / 64)), 256, 0, stream>>>(
        ws + Q_OFF, ws + KT_OFF, ws + V_OFF, maskp, ws + AT_OFF);
    outproj_kernel<<<dim3(16, 64), 256, 0, stream>>>(ws + AT_OFF, Wo, out);
}

// Round 2
// 425.051 us; speedup vs baseline: 5.4891x; 5.4891x over previous
//
#include <hip/hip_runtime.h>
#include <math.h>

typedef __attribute__((ext_vector_type(8))) short bf16x8;
typedef __attribute__((ext_vector_type(4))) float f32x4;

#define B_    2
#define T_    2048
#define DIM_  1024
#define H_    16
#define KV_   4
#define HD_   64

// Workspace layout:
//   Q   bf16 [B][H][T][64]    4,194,304 elems
//   K   bf16 [B][KV][T][64]   1,048,576 elems  (RoPE applied, row-major)
//   Vt  bf16 [B][KV][64][T]   1,048,576 elems  (transposed: d-major)
//   attn f32 [B][T][DIM]      4,194,304 elems

static __device__ __forceinline__ unsigned short f2bf(float f) {
    union { float f; unsigned int u; } v; v.f = f;
    unsigned int r = v.u + 0x7fff + ((v.u >> 16) & 1);   // RNE
    return (unsigned short)(r >> 16);
}

// ---------------------------------------------------------------------------
// Kernel 1: QKV projection (f32 core) + RoPE + bf16 epilogue.
// C[4096][1536] = x @ [Wq|Wk|Wv], 64x64 tiles, BK=16, 4x4/thread.
// ---------------------------------------------------------------------------
__global__ __launch_bounds__(256) void qkv_rope_kernel(
    const float* __restrict__ x, const float* __restrict__ sinp,
    const float* __restrict__ cosp,
    const float* __restrict__ Wq, const float* __restrict__ Wk,
    const float* __restrict__ Wv,
    unsigned short* __restrict__ Qw, unsigned short* __restrict__ Kw,
    unsigned short* __restrict__ Vtw)
{
    __shared__ float As[16][68];
    __shared__ float Bs[16][68];
    __shared__ float Ts[64][65];    // V transpose staging

    const int bn = blockIdx.x;     // 0..23
    const int bm = blockIdx.y;     // 0..63
    const int tid = threadIdx.x;
    const int m0 = bm * 64;

    const float* W; int ldw, c0;
    if (bn < 16)      { W = Wq; ldw = DIM_;     c0 = bn * 64;        }
    else if (bn < 20) { W = Wk; ldw = KV_*HD_;  c0 = bn * 64 - 1024; }
    else              { W = Wv; ldw = KV_*HD_;  c0 = bn * 64 - 1280; }

    const int lrow = tid >> 2;
    const int lkc  = (tid & 3) * 4;
    const int brow = tid >> 4;
    const int bcol = (tid & 15) * 4;
    const int tr = (tid >> 4) * 4;
    const int tc = (tid & 15) * 4;

    float acc[4][4] = {};

    for (int k0 = 0; k0 < DIM_; k0 += 16) {
        float4 av = *(const float4*)&x[(size_t)(m0 + lrow) * DIM_ + k0 + lkc];
        float4 bv = *(const float4*)&W[(size_t)(k0 + brow) * ldw + c0 + bcol];
        __syncthreads();
        As[lkc + 0][lrow] = av.x; As[lkc + 1][lrow] = av.y;
        As[lkc + 2][lrow] = av.z; As[lkc + 3][lrow] = av.w;
        *(float4*)&Bs[brow][bcol] = bv;
        __syncthreads();
        #pragma unroll
        for (int kk = 0; kk < 16; ++kk) {
            float4 a = *(const float4*)&As[kk][tr];
            float4 b = *(const float4*)&Bs[kk][tc];
            float af[4] = {a.x, a.y, a.z, a.w};
            float bf[4] = {b.x, b.y, b.z, b.w};
            #pragma unroll
            for (int i = 0; i < 4; ++i)
                #pragma unroll
                for (int j = 0; j < 4; ++j)
                    acc[i][j] += af[i] * bf[j];
        }
    }

    if (bn < 20) {
        // Q or K with RoPE; pack bf16 pairs into one 4B store
        #pragma unroll
        for (int i = 0; i < 4; ++i) {
            int m = m0 + tr + i;
            int b = m >> 11, t = m & 2047;
            int col = c0 + tc;
            int d = col & 63;
            #pragma unroll
            for (int jp = 0; jp < 2; ++jp) {
                int j = jp * 2;
                float ve = acc[i][j], vo = acc[i][j + 1];
                float ce = cosp[t * HD_ + d + j],     se = sinp[t * HD_ + d + j];
                float co = cosp[t * HD_ + d + j + 1], so = sinp[t * HD_ + d + j + 1];
                float re = ve * ce - vo * se;
                float ro = vo * co + ve * so;
                unsigned int pk = (unsigned int)f2bf(re) | ((unsigned int)f2bf(ro) << 16);
                if (bn < 16) {
                    int h = col >> 6;
                    *(unsigned int*)(Qw + ((((size_t)b * H_ + h) * T_ + t) * HD_ + d + j)) = pk;
                } else {
                    int kv = col >> 6;
                    *(unsigned int*)(Kw + ((((size_t)b * KV_ + kv) * T_ + t) * HD_ + d + j)) = pk;
                }
            }
        }
    } else {
        // V: transpose through LDS, coalesced bf16 stores to Vt[d][t]
        __syncthreads();
        #pragma unroll
        for (int i = 0; i < 4; ++i)
            #pragma unroll
            for (int j = 0; j < 4; ++j)
                Ts[tc + j][tr + i] = acc[i][j];
        __syncthreads();
        const int kv = c0 >> 6;
        const int b  = m0 >> 11;
        const int dl = tid >> 2;          // 0..63
        const int t0 = (tid & 3) * 16;    // 0..48
        unsigned short* dst = Vtw + (((size_t)b * KV_ + kv) * HD_ + dl) * T_ + (m0 & 2047) + t0;
        #pragma unroll
        for (int seg = 0; seg < 2; ++seg) {
            unsigned short u[8];
            #pragma unroll
            for (int e = 0; e < 8; ++e) u[e] = f2bf(Ts[dl][t0 + seg * 8 + e]);
            *(bf16x8*)(dst + seg * 8) = *(bf16x8*)u;
        }
    }
}

// ---------------------------------------------------------------------------
// Kernel 2: causal GQA flash attention, bf16 MFMA (16x16x32), f32 accum.
// Block = 4 waves, one (b,h) x 64 q-rows; wave owns 16 rows.
// ---------------------------------------------------------------------------
__global__ __launch_bounds__(256) void attn_kernel(
    const unsigned short* __restrict__ Qg, const unsigned short* __restrict__ Kg,
    const unsigned short* __restrict__ Vtg, const float* __restrict__ maskp,
    float* __restrict__ attn_out)
{
    __shared__ __align__(16) unsigned char Kl[8192];   // [key][d] bf16, XOR-swizzled
    __shared__ __align__(16) unsigned char Vl[8192];   // [d][key] bf16, XOR-swizzled
    __shared__ __align__(16) unsigned char Pl[4][2048]; // per-wave [16 q][64 k] bf16, swizzled

    const int tid  = threadIdx.x;
    const int lane = tid & 63;
    const int w    = tid >> 6;
    const int lr   = lane & 15;
    const int lg   = lane >> 4;

    const int bi = blockIdx.x;
    const int qt = 31 - (bi & 31);
    const int bh = bi >> 5;
    const int h  = bh & 15;
    const int b  = bh >> 4;
    const int kvh = h >> 2;
    const int q0 = qt * 64;

    // Q fragments (A: row = lane&15, k = (lane>>4)*8+j), reused all tiles
    const unsigned short* Qbase =
        Qg + (((size_t)b * H_ + h) * T_ + q0 + w * 16 + lr) * HD_;
    bf16x8 qf0 = *(const bf16x8*)(Qbase + lg * 8);
    bf16x8 qf1 = *(const bf16x8*)(Qbase + 32 + lg * 8);

    const unsigned short* Kb = Kg  + ((size_t)b * KV_ + kvh) * T_ * HD_;
    const unsigned short* Vb = Vtg + ((size_t)b * KV_ + kvh) * HD_ * T_;

    f32x4 o[4];
    float m[4], lsum[4];
    #pragma unroll
    for (int n = 0; n < 4; ++n) o[n] = (f32x4){0.f, 0.f, 0.f, 0.f};
    #pragma unroll
    for (int r = 0; r < 4; ++r) { m[r] = -1e30f; lsum[r] = 0.f; }

    const int qrow_base = q0 + w * 16 + lg * 4;
    unsigned char* Pw = &Pl[w][0];

    for (int kt = 0; kt <= qt; ++kt) {
        const int k0 = kt * 64;
        __syncthreads();
        // stage K[64 key][64 d] and Vt[64 d][64 key] tiles, swizzled
        #pragma unroll
        for (int it = 0; it < 2; ++it) {
            int c    = tid + it * 256;
            int row  = c >> 3;
            int colB = (c & 7) * 16;
            int swz  = (row * 128 + colB) ^ ((row & 7) << 4);
            float4 kv4 = *(const float4*)((const char*)(Kb + (size_t)(k0 + row) * HD_) + colB);
            *(float4*)(Kl + swz) = kv4;
            float4 vv4 = *(const float4*)((const char*)(Vb + (size_t)row * T_ + k0) + colB);
            *(float4*)(Vl + swz) = vv4;
        }
        __syncthreads();

        // QK^T: S[16 q][64 key] per wave
        f32x4 s[4];
        #pragma unroll
        for (int n = 0; n < 4; ++n) s[n] = (f32x4){0.f, 0.f, 0.f, 0.f};
        #pragma unroll
        for (int n = 0; n < 4; ++n) {
            const int key = 16 * n + lr;
            #pragma unroll
            for (int ks = 0; ks < 2; ++ks) {
                bf16x8 kb = *(const bf16x8*)(Kl +
                    ((key * 128 + 64 * ks + lg * 16) ^ ((key & 7) << 4)));
                s[n] = __builtin_amdgcn_mfma_f32_16x16x32_bf16(
                    ks == 0 ? qf0 : qf1, kb, s[n], 0, 0, 0);
            }
        }

        // mask + scale
        #pragma unroll
        for (int n = 0; n < 4; ++n) {
            const int keyg = k0 + 16 * n + lr;
            const float mv = maskp[b * T_ + keyg];
            #pragma unroll
            for (int r = 0; r < 4; ++r) {
                bool ok = (keyg <= qrow_base + r) && (mv > 0.f);
                s[n][r] = ok ? s[n][r] * 0.125f : -1e30f;
            }
        }

        // online softmax (rows split across 16-lane groups: xor 1,2,4,8)
        float p[4][4];
        #pragma unroll
        for (int r = 0; r < 4; ++r) {
            float rmax = fmaxf(fmaxf(s[0][r], s[1][r]), fmaxf(s[2][r], s[3][r]));
            rmax = fmaxf(rmax, __shfl_xor(rmax, 1));
            rmax = fmaxf(rmax, __shfl_xor(rmax, 2));
            rmax = fmaxf(rmax, __shfl_xor(rmax, 4));
            rmax = fmaxf(rmax, __shfl_xor(rmax, 8));
            float mnew  = fmaxf(m[r], rmax);
            float alpha = __expf(m[r] - mnew);
            m[r] = mnew;
            float rsum = 0.f;
            #pragma unroll
            for (int n = 0; n < 4; ++n) {
                float pv = __expf(s[n][r] - mnew);
                p[n][r] = pv;
                rsum += pv;
            }
            rsum += __shfl_xor(rsum, 1);
            rsum += __shfl_xor(rsum, 2);
            rsum += __shfl_xor(rsum, 4);
            rsum += __shfl_xor(rsum, 8);
            lsum[r] = lsum[r] * alpha + rsum;
            #pragma unroll
            for (int n = 0; n < 4; ++n) o[n][r] *= alpha;
        }

        // P -> wave-private LDS (bf16, swizzled), reshape to A-fragment
        #pragma unroll
        for (int n = 0; n < 4; ++n) {
            const int ky2 = (16 * n + lr) * 2;
            #pragma unroll
            for (int r = 0; r < 4; ++r) {
                const int qr = lg * 4 + r;
                *(unsigned short*)(Pw + ((qr * 128 + ky2) ^ ((qr & 7) << 4))) =
                    f2bf(p[n][r]);
            }
        }
        bf16x8 pa0 = *(const bf16x8*)(Pw + ((lr * 128 +      lg * 16) ^ ((lr & 7) << 4)));
        bf16x8 pa1 = *(const bf16x8*)(Pw + ((lr * 128 + 64 + lg * 16) ^ ((lr & 7) << 4)));

        // PV: O[16 q][64 d] += P @ V
        #pragma unroll
        for (int n = 0; n < 4; ++n) {
            const int d = 16 * n + lr;
            #pragma unroll
            for (int ks = 0; ks < 2; ++ks) {
                bf16x8 vb = *(const bf16x8*)(Vl +
                    ((d * 128 + 64 * ks + lg * 16) ^ ((d & 7) << 4)));
                o[n] = __builtin_amdgcn_mfma_f32_16x16x32_bf16(
                    ks == 0 ? pa0 : pa1, vb, o[n], 0, 0, 0);
            }
        }
    }

    #pragma unroll
    for (int n = 0; n < 4; ++n)
        #pragma unroll
        for (int r = 0; r < 4; ++r) {
            int q = q0 + w * 16 + lg * 4 + r;
            attn_out[((size_t)b * T_ + q) * DIM_ + h * HD_ + 16 * n + lr] =
                o[n][r] / lsum[r];
        }
}

// ---------------------------------------------------------------------------
// Kernel 3: output projection (f32). d_out = attn @ Wo
// ---------------------------------------------------------------------------
__global__ __launch_bounds__(256) void outproj_kernel(
    const float* __restrict__ A, const float* __restrict__ Wo,
    float* __restrict__ out)
{
    __shared__ float As[16][68];
    __shared__ float Bs[16][68];

    const int bn = blockIdx.x;
    const int bm = blockIdx.y;
    const int tid = threadIdx.x;
    const int m0 = bm * 64, n0 = bn * 64;

    const int lrow = tid >> 2;
    const int lkc  = (tid & 3) * 4;
    const int brow = tid >> 4;
    const int bcol = (tid & 15) * 4;
    const int tr = (tid >> 4) * 4;
    const int tc = (tid & 15) * 4;

    float acc[4][4] = {};

    for (int k0 = 0; k0 < DIM_; k0 += 16) {
        float4 av = *(const float4*)&A[(size_t)(m0 + lrow) * DIM_ + k0 + lkc];
        float4 bv = *(const float4*)&Wo[(size_t)(k0 + brow) * DIM_ + n0 + bcol];
        __syncthreads();
        As[lkc + 0][lrow] = av.x; As[lkc + 1][lrow] = av.y;
        As[lkc + 2][lrow] = av.z; As[lkc + 3][lrow] = av.w;
        *(float4*)&Bs[brow][bcol] = bv;
        __syncthreads();
        #pragma unroll
        for (int kk = 0; kk < 16; ++kk) {
            float4 a = *(const float4*)&As[kk][tr];
            float4 b = *(const float4*)&Bs[kk][tc];
            float af[4] = {a.x, a.y, a.z, a.w};
            float bf[4] = {b.x, b.y, b.z, b.w};
            #pragma unroll
            for (int i = 0; i < 4; ++i)
                #pragma unroll
                for (int j = 0; j < 4; ++j)
                    acc[i][j] += af[i] * bf[j];
        }
    }

    #pragma unroll
    for (int i = 0; i < 4; ++i) {
        size_t mrow = m0 + tr + i;
        *(float4*)&out[mrow * DIM_ + n0 + tc] =
            make_float4(acc[i][0], acc[i][1], acc[i][2], acc[i][3]);
    }
}

// ---------------------------------------------------------------------------
extern "C" void kernel_launch(void* const* d_in, const int* in_sizes, int n_in,
                              void* d_out, int out_size, void* d_ws, size_t ws_size,
                              hipStream_t stream)
{
    const float* x     = (const float*)d_in[0];
    const float* sinp  = (const float*)d_in[1];
    const float* cosp  = (const float*)d_in[2];
    const float* maskp = (const float*)d_in[3];
    const float* Wq    = (const float*)d_in[4];
    const float* Wk    = (const float*)d_in[5];
    const float* Wv    = (const float*)d_in[6];
    const float* Wo    = (const float*)d_in[7];

    unsigned short* Qw  = (unsigned short*)d_ws;       // 4,194,304 bf16
    unsigned short* Kw  = Qw + 4194304;                // 1,048,576 bf16
    unsigned short* Vtw = Kw + 1048576;                // 1,048,576 bf16
    float* attn         = (float*)(Vtw + 1048576);     // 4,194,304 f32
    float* out = (float*)d_out;

    qkv_rope_kernel<<<dim3(24, 64), 256, 0, stream>>>(x, sinp, cosp, Wq, Wk, Wv,
                                                      Qw, Kw, Vtw);
    attn_kernel<<<dim3(B_ * H_ * (T_ / 64)), 256, 0, stream>>>(
        Qw, Kw, Vtw, maskp, attn);
    outproj_kernel<<<dim3(16, 64), 256, 0, stream>>>(attn, Wo, out);
}

// Round 3
// 181.397 us; speedup vs baseline: 12.8620x; 2.3432x over previous
//
#include <hip/hip_runtime.h>
#include <math.h>

typedef __attribute__((ext_vector_type(8))) short bf16x8;
typedef __attribute__((ext_vector_type(4))) float f32x4;
typedef __attribute__((ext_vector_type(4))) unsigned short u16x4;

#define B_    2
#define T_    2048
#define DIM_  1024
#define H_    16
#define KV_   4
#define HD_   64

static __device__ __forceinline__ unsigned short f2bf(float f) {
    union { float f; unsigned int u; } v; v.f = f;
    unsigned int r = v.u + 0x7fff + ((v.u >> 16) & 1);   // RNE
    return (unsigned short)(r >> 16);
}

static __device__ __forceinline__ void gload16(const void* g, void* l) {
    __builtin_amdgcn_global_load_lds(
        (const __attribute__((address_space(1))) unsigned int*)g,
        (__attribute__((address_space(3))) unsigned int*)l, 16, 0, 0);
}

// Workspace (unsigned short elements):
//   xb   bf16 [4096][1024]          off 0
//   Wt   bf16 [1536][1024]          off 4194304   (Wq^T | Wk^T | Wv^T rows)
//   Wot  bf16 [1024][1024]          off 5767168
//   Q    bf16 [B][H][T][64]         off 6815744
//   K    bf16 [B][KV][T][64]        off 11010048
//   Vt   bf16 [B][KV][64][T]        off 12058624
//   attnb bf16 [B][T][DIM]          off 13107200
#define XB_OFF   0u
#define WT_OFF   4194304u
#define WOT_OFF  5767168u
#define QB_OFF   6815744u
#define KB_OFF   11010048u
#define VTB_OFF  12058624u
#define AB_OFF   13107200u

// ---------------------------------------------------------------------------
// Pre-pass: f32 -> bf16 convert (8 elems/thread)
// ---------------------------------------------------------------------------
__global__ __launch_bounds__(256) void cvt_kernel(
    const float* __restrict__ in, unsigned short* __restrict__ out)
{
    const size_t i = ((size_t)blockIdx.x * 256 + threadIdx.x) * 8;
    float4 a = *(const float4*)&in[i];
    float4 b = *(const float4*)&in[i + 4];
    unsigned short u[8] = {f2bf(a.x), f2bf(a.y), f2bf(a.z), f2bf(a.w),
                           f2bf(b.x), f2bf(b.y), f2bf(b.z), f2bf(b.w)};
    *(bf16x8*)&out[i] = *(bf16x8*)u;
}

// ---------------------------------------------------------------------------
// Pre-pass: W f32 [1024][N] -> Wt bf16 [N][1024]  (64x64 LDS tile transpose)
// ---------------------------------------------------------------------------
__global__ __launch_bounds__(256) void wtrans_kernel(
    const float* __restrict__ W, unsigned short* __restrict__ Wt, int N)
{
    __shared__ float Ts[64][65];
    const int n0 = blockIdx.x * 64, k0 = blockIdx.y * 64;
    const int tid = threadIdx.x;
    const int r = tid >> 4, c4 = (tid & 15) * 4;
    #pragma unroll
    for (int i = 0; i < 4; ++i) {
        float4 v = *(const float4*)&W[(size_t)(k0 + r + 16 * i) * N + n0 + c4];
        Ts[r + 16 * i][c4 + 0] = v.x; Ts[r + 16 * i][c4 + 1] = v.y;
        Ts[r + 16 * i][c4 + 2] = v.z; Ts[r + 16 * i][c4 + 3] = v.w;
    }
    __syncthreads();
    const int rn = tid >> 3, ck = (tid & 7) * 8;
    #pragma unroll
    for (int i = 0; i < 2; ++i) {
        int n = rn + 32 * i;
        unsigned short u[8];
        #pragma unroll
        for (int e = 0; e < 8; ++e) u[e] = f2bf(Ts[ck + e][n]);
        *(bf16x8*)&Wt[(size_t)(n0 + n) * 1024 + k0 + ck] = *(bf16x8*)u;
    }
}

// ---------------------------------------------------------------------------
// Kernel 1: QKV bf16 MFMA GEMM + RoPE epilogue.
// C[4096][1536] = xb @ Wt^T. 128x128 tile, BK=64, 4 waves of 64x64.
// ---------------------------------------------------------------------------
__global__ __launch_bounds__(256) void qkv_mfma_kernel(
    const unsigned short* __restrict__ xb, const unsigned short* __restrict__ Wt,
    const float* __restrict__ sinp, const float* __restrict__ cosp,
    unsigned short* __restrict__ Qw, unsigned short* __restrict__ Kw,
    unsigned short* __restrict__ Vtw)
{
    __shared__ __align__(16) unsigned char As[16384];   // [128 m][128B], XOR-swizzled
    __shared__ __align__(16) unsigned char Bs[16384];   // [128 n][128B]

    const int tid = threadIdx.x, lane = tid & 63, w = tid >> 6;
    const int lr = lane & 15, lg = lane >> 4;
    const int wm = w >> 1, wn = w & 1;
    const int bn = blockIdx.x, bm = blockIdx.y;
    const int m0 = bm * 128, n0 = bn * 128;

    const int chunkR = lane >> 3;                    // row within 8-row chunk
    const int srcOff = 8 * ((lane & 7) ^ chunkR);    // inverse-swizzled src (elems)

    f32x4 acc[4][4] = {};

    for (int k0 = 0; k0 < 1024; k0 += 64) {
        __syncthreads();
        #pragma unroll
        for (int i = 0; i < 4; ++i) {
            const int chunk = w * 4 + i;
            const int row = chunk * 8 + chunkR;
            gload16(xb + (size_t)(m0 + row) * 1024 + k0 + srcOff, As + chunk * 1024);
            gload16(Wt + (size_t)(n0 + row) * 1024 + k0 + srcOff, Bs + chunk * 1024);
        }
        __syncthreads();   // compiler drains vmcnt before s_barrier
        #pragma unroll
        for (int kk = 0; kk < 2; ++kk) {
            bf16x8 af[4], bfr[4];
            #pragma unroll
            for (int mf = 0; mf < 4; ++mf) {
                const int row = wm * 64 + mf * 16 + lr;
                af[mf] = *(const bf16x8*)(As + row * 128 +
                          ((kk * 64 + lg * 16) ^ ((row & 7) << 4)));
            }
            #pragma unroll
            for (int nf = 0; nf < 4; ++nf) {
                const int row = wn * 64 + nf * 16 + lr;
                bfr[nf] = *(const bf16x8*)(Bs + row * 128 +
                          ((kk * 64 + lg * 16) ^ ((row & 7) << 4)));
            }
            #pragma unroll
            for (int mf = 0; mf < 4; ++mf)
                #pragma unroll
                for (int nf = 0; nf < 4; ++nf)
                    acc[mf][nf] = __builtin_amdgcn_mfma_f32_16x16x32_bf16(
                        af[mf], bfr[nf], acc[mf][nf], 0, 0, 0);
        }
    }

    // Epilogue: C row m = m0+wm*64+mf*16+lg*4+r, col = n0+wn*64+nf*16+lr
    const float rsign = (lane & 1) ? 1.f : -1.f;
    #pragma unroll
    for (int nf = 0; nf < 4; ++nf) {
        const int col = n0 + wn * 64 + nf * 16 + lr;
        #pragma unroll
        for (int mf = 0; mf < 4; ++mf) {
            const int mrow = m0 + wm * 64 + mf * 16 + lg * 4;
            const int b = mrow >> 11;
            const int t0 = mrow & 2047;
            if (col < 1280) {   // Q or K: RoPE (block-uniform branch)
                const int d = col & 63;
                #pragma unroll
                for (int r = 0; r < 4; ++r) {
                    float val = acc[mf][nf][r];
                    float partner = __shfl_xor(val, 1);
                    const int t = t0 + r;
                    float cs = cosp[t * 64 + d], sn = sinp[t * 64 + d];
                    unsigned short ub = f2bf(val * cs + rsign * partner * sn);
                    if (col < 1024) {
                        const int h = col >> 6;
                        Qw[(((size_t)b * H_ + h) * T_ + t) * 64 + d] = ub;
                    } else {
                        const int kv = (col - 1024) >> 6;
                        Kw[(((size_t)b * KV_ + kv) * T_ + t) * 64 + d] = ub;
                    }
                }
            } else {            // V: transposed store, 4 consecutive t packed
                const int cv = col - 1280, kv = cv >> 6, d = cv & 63;
                unsigned short u[4];
                #pragma unroll
                for (int r = 0; r < 4; ++r) u[r] = f2bf(acc[mf][nf][r]);
                *(u16x4*)&Vtw[(((size_t)b * KV_ + kv) * 64 + d) * T_ + t0] =
                    *(u16x4*)u;
            }
        }
    }
}

// ---------------------------------------------------------------------------
// Kernel 2: causal GQA flash attention, bf16 MFMA, f32 accum. (bf16 output)
// ---------------------------------------------------------------------------
__global__ __launch_bounds__(256) void attn_kernel(
    const unsigned short* __restrict__ Qg, const unsigned short* __restrict__ Kg,
    const unsigned short* __restrict__ Vtg, const float* __restrict__ maskp,
    unsigned short* __restrict__ attn_out)
{
    __shared__ __align__(16) unsigned char Kl[8192];
    __shared__ __align__(16) unsigned char Vl[8192];
    __shared__ __align__(16) unsigned char Pl[4][2048];

    const int tid  = threadIdx.x;
    const int lane = tid & 63;
    const int w    = tid >> 6;
    const int lr   = lane & 15;
    const int lg   = lane >> 4;

    const int bi = blockIdx.x;
    const int qt = 31 - (bi & 31);
    const int bh = bi >> 5;
    const int h  = bh & 15;
    const int b  = bh >> 4;
    const int kvh = h >> 2;
    const int q0 = qt * 64;

    const unsigned short* Qbase =
        Qg + (((size_t)b * H_ + h) * T_ + q0 + w * 16 + lr) * HD_;
    bf16x8 qf0 = *(const bf16x8*)(Qbase + lg * 8);
    bf16x8 qf1 = *(const bf16x8*)(Qbase + 32 + lg * 8);

    const unsigned short* Kb = Kg  + ((size_t)b * KV_ + kvh) * T_ * HD_;
    const unsigned short* Vb = Vtg + ((size_t)b * KV_ + kvh) * HD_ * T_;

    f32x4 o[4];
    float m[4], lsum[4];
    #pragma unroll
    for (int n = 0; n < 4; ++n) o[n] = (f32x4){0.f, 0.f, 0.f, 0.f};
    #pragma unroll
    for (int r = 0; r < 4; ++r) { m[r] = -1e30f; lsum[r] = 0.f; }

    const int qrow_base = q0 + w * 16 + lg * 4;
    unsigned char* Pw = &Pl[w][0];

    for (int kt = 0; kt <= qt; ++kt) {
        const int k0 = kt * 64;
        __syncthreads();
        #pragma unroll
        for (int it = 0; it < 2; ++it) {
            int c    = tid + it * 256;
            int row  = c >> 3;
            int colB = (c & 7) * 16;
            int swz  = (row * 128 + colB) ^ ((row & 7) << 4);
            float4 kv4 = *(const float4*)((const char*)(Kb + (size_t)(k0 + row) * HD_) + colB);
            *(float4*)(Kl + swz) = kv4;
            float4 vv4 = *(const float4*)((const char*)(Vb + (size_t)row * T_ + k0) + colB);
            *(float4*)(Vl + swz) = vv4;
        }
        __syncthreads();

        f32x4 s[4];
        #pragma unroll
        for (int n = 0; n < 4; ++n) s[n] = (f32x4){0.f, 0.f, 0.f, 0.f};
        #pragma unroll
        for (int n = 0; n < 4; ++n) {
            const int key = 16 * n + lr;
            #pragma unroll
            for (int ks = 0; ks < 2; ++ks) {
                bf16x8 kb = *(const bf16x8*)(Kl +
                    ((key * 128 + 64 * ks + lg * 16) ^ ((key & 7) << 4)));
                s[n] = __builtin_amdgcn_mfma_f32_16x16x32_bf16(
                    ks == 0 ? qf0 : qf1, kb, s[n], 0, 0, 0);
            }
        }

        #pragma unroll
        for (int n = 0; n < 4; ++n) {
            const int keyg = k0 + 16 * n + lr;
            const float mv = maskp[b * T_ + keyg];
            #pragma unroll
            for (int r = 0; r < 4; ++r) {
                bool ok = (keyg <= qrow_base + r) && (mv > 0.f);
                s[n][r] = ok ? s[n][r] * 0.125f : -1e30f;
            }
        }

        float p[4][4];
        #pragma unroll
        for (int r = 0; r < 4; ++r) {
            float rmax = fmaxf(fmaxf(s[0][r], s[1][r]), fmaxf(s[2][r], s[3][r]));
            rmax = fmaxf(rmax, __shfl_xor(rmax, 1));
            rmax = fmaxf(rmax, __shfl_xor(rmax, 2));
            rmax = fmaxf(rmax, __shfl_xor(rmax, 4));
            rmax = fmaxf(rmax, __shfl_xor(rmax, 8));
            float mnew  = fmaxf(m[r], rmax);
            float alpha = __expf(m[r] - mnew);
            m[r] = mnew;
            float rsum = 0.f;
            #pragma unroll
            for (int n = 0; n < 4; ++n) {
                float pv = __expf(s[n][r] - mnew);
                p[n][r] = pv;
                rsum += pv;
            }
            rsum += __shfl_xor(rsum, 1);
            rsum += __shfl_xor(rsum, 2);
            rsum += __shfl_xor(rsum, 4);
            rsum += __shfl_xor(rsum, 8);
            lsum[r] = lsum[r] * alpha + rsum;
            #pragma unroll
            for (int n = 0; n < 4; ++n) o[n][r] *= alpha;
        }

        #pragma unroll
        for (int n = 0; n < 4; ++n) {
            const int ky2 = (16 * n + lr) * 2;
            #pragma unroll
            for (int r = 0; r < 4; ++r) {
                const int qr = lg * 4 + r;
                *(unsigned short*)(Pw + ((qr * 128 + ky2) ^ ((qr & 7) << 4))) =
                    f2bf(p[n][r]);
            }
        }
        bf16x8 pa0 = *(const bf16x8*)(Pw + ((lr * 128 +      lg * 16) ^ ((lr & 7) << 4)));
        bf16x8 pa1 = *(const bf16x8*)(Pw + ((lr * 128 + 64 + lg * 16) ^ ((lr & 7) << 4)));

        #pragma unroll
        for (int n = 0; n < 4; ++n) {
            const int d = 16 * n + lr;
            #pragma unroll
            for (int ks = 0; ks < 2; ++ks) {
                bf16x8 vb = *(const bf16x8*)(Vl +
                    ((d * 128 + 64 * ks + lg * 16) ^ ((d & 7) << 4)));
                o[n] = __builtin_amdgcn_mfma_f32_16x16x32_bf16(
                    ks == 0 ? pa0 : pa1, vb, o[n], 0, 0, 0);
            }
        }
    }

    #pragma unroll
    for (int n = 0; n < 4; ++n)
        #pragma unroll
        for (int r = 0; r < 4; ++r) {
            int q = q0 + w * 16 + lg * 4 + r;
            attn_out[((size_t)b * T_ + q) * DIM_ + h * HD_ + 16 * n + lr] =
                f2bf(o[n][r] / lsum[r]);
        }
}

// ---------------------------------------------------------------------------
// Kernel 3: output projection bf16 MFMA. d_out = attnb @ Wot^T (f32 out)
// ---------------------------------------------------------------------------
__global__ __launch_bounds__(256) void outproj_mfma_kernel(
    const unsigned short* __restrict__ Ab, const unsigned short* __restrict__ Wot,
    float* __restrict__ out)
{
    __shared__ __align__(16) unsigned char As[16384];
    __shared__ __align__(16) unsigned char Bs[16384];

    const int tid = threadIdx.x, lane = tid & 63, w = tid >> 6;
    const int lr = lane & 15, lg = lane >> 4;
    const int wm = w >> 1, wn = w & 1;
    const int bn = blockIdx.x, bm = blockIdx.y;
    const int m0 = bm * 128, n0 = bn * 128;

    const int chunkR = lane >> 3;
    const int srcOff = 8 * ((lane & 7) ^ chunkR);

    f32x4 acc[4][4] = {};

    for (int k0 = 0; k0 < 1024; k0 += 64) {
        __syncthreads();
        #pragma unroll
        for (int i = 0; i < 4; ++i) {
            const int chunk = w * 4 + i;
            const int row = chunk * 8 + chunkR;
            gload16(Ab  + (size_t)(m0 + row) * 1024 + k0 + srcOff, As + chunk * 1024);
            gload16(Wot + (size_t)(n0 + row) * 1024 + k0 + srcOff, Bs + chunk * 1024);
        }
        __syncthreads();
        #pragma unroll
        for (int kk = 0; kk < 2; ++kk) {
            bf16x8 af[4], bfr[4];
            #pragma unroll
            for (int mf = 0; mf < 4; ++mf) {
                const int row = wm * 64 + mf * 16 + lr;
                af[mf] = *(const bf16x8*)(As + row * 128 +
                          ((kk * 64 + lg * 16) ^ ((row & 7) << 4)));
            }
            #pragma unroll
            for (int nf = 0; nf < 4; ++nf) {
                const int row = wn * 64 + nf * 16 + lr;
                bfr[nf] = *(const bf16x8*)(Bs + row * 128 +
                          ((kk * 64 + lg * 16) ^ ((row & 7) << 4)));
            }
            #pragma unroll
            for (int mf = 0; mf < 4; ++mf)
                #pragma unroll
                for (int nf = 0; nf < 4; ++nf)
                    acc[mf][nf] = __builtin_amdgcn_mfma_f32_16x16x32_bf16(
                        af[mf], bfr[nf], acc[mf][nf], 0, 0, 0);
        }
    }

    #pragma unroll
    for (int nf = 0; nf < 4; ++nf) {
        const int col = n0 + wn * 64 + nf * 16 + lr;
        #pragma unroll
        for (int mf = 0; mf < 4; ++mf) {
            const int mrow = m0 + wm * 64 + mf * 16 + lg * 4;
            #pragma unroll
            for (int r = 0; r < 4; ++r)
                out[(size_t)(mrow + r) * 1024 + col] = acc[mf][nf][r];
        }
    }
}

// ---------------------------------------------------------------------------
extern "C" void kernel_launch(void* const* d_in, const int* in_sizes, int n_in,
                              void* d_out, int out_size, void* d_ws, size_t ws_size,
                              hipStream_t stream)
{
    const float* x     = (const float*)d_in[0];
    const float* sinp  = (const float*)d_in[1];
    const float* cosp  = (const float*)d_in[2];
    const float* maskp = (const float*)d_in[3];
    const float* Wq    = (const float*)d_in[4];
    const float* Wk    = (const float*)d_in[5];
    const float* Wv    = (const float*)d_in[6];
    const float* Wo    = (const float*)d_in[7];

    unsigned short* wsb = (unsigned short*)d_ws;
    unsigned short* xb  = wsb + XB_OFF;
    unsigned short* Wt  = wsb + WT_OFF;
    unsigned short* Wot = wsb + WOT_OFF;
    unsigned short* Qw  = wsb + QB_OFF;
    unsigned short* Kw  = wsb + KB_OFF;
    unsigned short* Vtw = wsb + VTB_OFF;
    unsigned short* Ab  = wsb + AB_OFF;
    float* out = (float*)d_out;

    cvt_kernel<<<2048, 256, 0, stream>>>(x, xb);
    wtrans_kernel<<<dim3(16, 16), 256, 0, stream>>>(Wq, Wt, 1024);
    wtrans_kernel<<<dim3(4, 16), 256, 0, stream>>>(Wk, Wt + 1024u * 1024u, 256);
    wtrans_kernel<<<dim3(4, 16), 256, 0, stream>>>(Wv, Wt + 1280u * 1024u, 256);
    wtrans_kernel<<<dim3(16, 16), 256, 0, stream>>>(Wo, Wot, 1024);

    qkv_mfma_kernel<<<dim3(12, 32), 256, 0, stream>>>(xb, Wt, sinp, cosp,
                                                      Qw, Kw, Vtw);
    attn_kernel<<<dim3(B_ * H_ * (T_ / 64)), 256, 0, stream>>>(
        Qw, Kw, Vtw, maskp, Ab);
    outproj_mfma_kernel<<<dim3(8, 32), 256, 0, stream>>>(Ab, Wot, out);
}